// Round 11
// baseline (83.535 us; speedup 1.0000x reference)
//
#include <hip/hip_runtime.h>
#include <math.h>

#define NB 2048
#define LL 200
#define PADL 256   // padded per-user slot stride (max needed 200+9*3=227)
#define DD 64
#define CC 9
#define HH 16
#define NW 4

// ---- d_ws layout (bytes) ----
// srow_g : int  [B*PADL]  @ 0          (2,097,152)
// z_g    : float[B*PADL]  @ 2,097,152  (2,097,152)
// cstart : int  [B*20]    @ 4,194,304  (163,840)   [0..9]=padded starts(+total), [10..18]=counts
// pre_g  : float[B*C*H]   @ 4,358,144  (1,179,648)
// total ~5.5 MB

// kA: per-user ballot sort (4-aligned padded groups) + pre = b1 + W1u.u
__global__ __launch_bounds__(256) void din_ka(
    const int* __restrict__ user_inputs,
    const int* __restrict__ record_inputs,
    const int* __restrict__ item_cat,
    const float* __restrict__ user_emb,
    const float* __restrict__ W1,
    const float* __restrict__ b1,
    int* __restrict__ srow_g,
    int* __restrict__ cstart_g,
    float* __restrict__ pre_g)
{
  const int b = blockIdx.x;
  const int t = threadIdx.x;
  const int wave = t >> 6, lane = t & 63;

  __shared__ float u_s[DD];
  __shared__ int   wcnt[NW][CC];
  __shared__ int   cstart[CC + 1];
  __shared__ int   ccnt[CC];

  int r = -1, c0 = -1;
  if (t < LL) {
    r = record_inputs[b * LL + t];
    if (r >= 0) c0 = item_cat[r];
  }
  if (t < DD) u_s[t] = user_emb[(size_t)user_inputs[b] * DD + t];

  srow_g[b * PADL + t] = 0;   // default rows for pad slots (row 0 is valid memory)

  int myrank = 0;
  #pragma unroll
  for (int c = 0; c < CC; ++c) {
    unsigned long long m = __ballot(c0 == c);
    if (lane == 0) wcnt[wave][c] = __popcll(m);
    if (c0 == c) myrank = __popcll(m & ((1ULL << lane) - 1ULL));
  }
  __syncthreads();

  if (t == 0) {
    int acc = 0;
    #pragma unroll
    for (int c = 0; c < CC; ++c) {
      cstart[c] = acc;
      int cn = wcnt[0][c] + wcnt[1][c] + wcnt[2][c] + wcnt[3][c];
      ccnt[c] = cn;
      acc = (acc + cn + 3) & ~3;   // 4-aligned next group
    }
    cstart[CC] = acc;
  }
  if (t < CC * HH) {   // pre = b1 + W1u . u  -> global
    int c = t / HH, j = t % HH;
    const float* wp = &W1[(size_t)(c * HH + j) * (2 * DD)];
    float acc = b1[c * HH + j];
    #pragma unroll 8
    for (int d = 0; d < DD; ++d) acc += wp[d] * u_s[d];
    pre_g[(size_t)(b * CC + c) * HH + j] = acc;
  }
  __syncthreads();

  if (c0 >= 0) {
    int off = cstart[c0];
    for (int w = 0; w < wave; ++w) off += wcnt[w][c0];
    srow_g[b * PADL + off + myrank] = r;
  }
  if (t < CC + 1) cstart_g[b * 20 + t] = cstart[t];
  else if (t < 2 * CC + 1) cstart_g[b * 20 + 10 + (t - CC - 1)] = ccnt[t - CC - 1];
}

// kB: 4 same-category items per thread; W1 e-half in LDS [ji][c].
__global__ __launch_bounds__(256) void din_kb(
    const float* __restrict__ item_emb,
    const float* __restrict__ W1,
    const float* __restrict__ W2,
    const float* __restrict__ b2,
    const int* __restrict__ srow_g,
    const int* __restrict__ cstart_g,
    const float* __restrict__ pre_g,
    float* __restrict__ z_g)
{
  const int t = threadIdx.x;

  __shared__ float4 w_lds[HH * 16 * CC];   // 36.9 KB
  __shared__ float  w2_s[CC * HH];
  __shared__ float  b2_s[CC];

  #pragma unroll
  for (int k = t; k < HH * 16 * CC; k += 256) {
    int c = k >> 8;
    int ji = k & 255;
    int j = ji >> 4, i = ji & 15;
    w_lds[ji * CC + c] = ((const float4*)W1)[(size_t)(c * HH + j) * 32 + 16 + i];
  }
  if (t < CC * HH) w2_s[t] = W2[t];
  if (t < CC) b2_s[t] = b2[t];
  __syncthreads();

  const int g = blockIdx.x * 256 + t;      // [0, B*64): one thread = 4 slots
  const int b = g >> 6;
  const int q4 = (g & 63) * 4;             // base slot (4-aligned)
  const int* cs = &cstart_g[b * 20];
  if (q4 >= cs[CC]) return;                // beyond padded total

  int c = 0;
  #pragma unroll
  for (int q = 0; q < CC - 1; ++q) c += (q4 >= cs[q + 1]) ? 1 : 0;

  const int base = b * PADL + q4;
  const int r0 = srow_g[base + 0], r1 = srow_g[base + 1];
  const int r2 = srow_g[base + 2], r3 = srow_g[base + 3];
  const float4* e0 = (const float4*)&item_emb[(size_t)r0 * DD];
  const float4* e1 = (const float4*)&item_emb[(size_t)r1 * DD];
  const float4* e2 = (const float4*)&item_emb[(size_t)r2 * DD];
  const float4* e3 = (const float4*)&item_emb[(size_t)r3 * DD];

  float acc0[HH], acc1[HH], acc2[HH], acc3[HH];
  {
    const float4* pp = (const float4*)&pre_g[(size_t)(b * CC + c) * HH];
    #pragma unroll
    for (int jq = 0; jq < 4; ++jq) {
      float4 pv = pp[jq];
      acc0[jq*4+0] = pv.x; acc0[jq*4+1] = pv.y; acc0[jq*4+2] = pv.z; acc0[jq*4+3] = pv.w;
      acc1[jq*4+0] = pv.x; acc1[jq*4+1] = pv.y; acc1[jq*4+2] = pv.z; acc1[jq*4+3] = pv.w;
      acc2[jq*4+0] = pv.x; acc2[jq*4+1] = pv.y; acc2[jq*4+2] = pv.z; acc2[jq*4+3] = pv.w;
      acc3[jq*4+0] = pv.x; acc3[jq*4+1] = pv.y; acc3[jq*4+2] = pv.z; acc3[jq*4+3] = pv.w;
    }
  }

  #pragma unroll
  for (int i = 0; i < 16; ++i) {
    float4 a0 = e0[i], a1 = e1[i], a2 = e2[i], a3 = e3[i];
    #pragma unroll
    for (int j = 0; j < HH; ++j) {
      float4 wv = w_lds[(j * 16 + i) * CC + c];
      acc0[j] += wv.x * a0.x + wv.y * a0.y + wv.z * a0.z + wv.w * a0.w;
      acc1[j] += wv.x * a1.x + wv.y * a1.y + wv.z * a1.z + wv.w * a1.w;
      acc2[j] += wv.x * a2.x + wv.y * a2.y + wv.z * a2.z + wv.w * a2.w;
      acc3[j] += wv.x * a3.x + wv.y * a3.y + wv.z * a3.z + wv.w * a3.w;
    }
  }

  float s0 = b2_s[c], s1 = s0, s2 = s0, s3 = s0;
  #pragma unroll
  for (int j = 0; j < HH; ++j) {
    float w2v = w2_s[c * HH + j];
    s0 += w2v * fmaxf(acc0[j], 0.f);
    s1 += w2v * fmaxf(acc1[j], 0.f);
    s2 += w2v * fmaxf(acc2[j], 0.f);
    s3 += w2v * fmaxf(acc3[j], 0.f);
  }
  *(float4*)&z_g[base] = make_float4(expf(s0), expf(s1), expf(s2), expf(s3));
}

// kCD: one block per user, 576 threads = 9 waves (wave = category).
// gvec via float4 lanes (16 lanes/row, 4 rows per wave-instruction, 8-deep ILP),
// then fused top-level attention + output.
__global__ __launch_bounds__(576) void din_kcd(
    const int* __restrict__ user_inputs,
    const int* __restrict__ item_inputs,
    const float* __restrict__ user_emb,
    const float* __restrict__ item_emb,
    const float* __restrict__ Wt1,
    const float* __restrict__ bt1,
    const float* __restrict__ Wt2,
    const float* __restrict__ bt2,
    const int* __restrict__ srow_g,
    const float* __restrict__ z_g,
    const int* __restrict__ cstart_g,
    float* __restrict__ out)
{
  const int b = blockIdx.x;
  const int t = threadIdx.x;
  const int c = t >> 6;            // wave = category
  const int lane = t & 63;
  const int g = lane >> 4;         // item subgroup 0..3
  const int h = lane & 15;         // d-quad index (d = 4h..4h+3)

  __shared__ float u_s[DD];
  __shared__ float gvec_s[CC][DD];
  __shared__ float h2_s[CC][HH];
  __shared__ float w2_s[CC];
  __shared__ int   cnt_s[CC];

  if (t < DD) u_s[t] = user_emb[(size_t)user_inputs[b] * DD + t];

  const int i0 = cstart_g[b * 20 + c];
  const int n  = cstart_g[b * 20 + 10 + c];
  if (lane == 0) cnt_s[c] = n;
  const int sb = b * PADL + i0;

  float4 acc = make_float4(0.f, 0.f, 0.f, 0.f);
  float  zs  = 0.f;

  for (int k = 0; k < n; k += 8) {
    // chunk A: items k..k+3
    const int iA = k + g;
    const float zA = (iA < n) ? z_g[sb + iA] : 0.f;
    const int   rA = srow_g[sb + iA];
    const float4 eA = *(const float4*)&item_emb[(size_t)rA * DD + 4 * h];
    // chunk B: items k+4..k+7 (wave-uniform guard)
    float zB = 0.f;
    float4 eB = make_float4(0.f, 0.f, 0.f, 0.f);
    if (k + 4 < n) {
      const int iB = k + 4 + g;
      zB = (iB < n) ? z_g[sb + iB] : 0.f;
      const int rB = srow_g[sb + iB];
      eB = *(const float4*)&item_emb[(size_t)rB * DD + 4 * h];
    }
    acc.x += zA * eA.x; acc.y += zA * eA.y; acc.z += zA * eA.z; acc.w += zA * eA.w;
    acc.x += zB * eB.x; acc.y += zB * eB.y; acc.z += zB * eB.z; acc.w += zB * eB.w;
    zs += zA; zs += zB;
  }

  // combine the 4 item-subgroups (lanes differ only in g): butterfly over bits 4,5
  acc.x += __shfl_xor(acc.x, 16, 64); acc.y += __shfl_xor(acc.y, 16, 64);
  acc.z += __shfl_xor(acc.z, 16, 64); acc.w += __shfl_xor(acc.w, 16, 64);
  acc.x += __shfl_xor(acc.x, 32, 64); acc.y += __shfl_xor(acc.y, 32, 64);
  acc.z += __shfl_xor(acc.z, 32, 64); acc.w += __shfl_xor(acc.w, 32, 64);
  zs += __shfl_xor(zs, 16, 64);
  zs += __shfl_xor(zs, 32, 64);

  if (g == 0) {
    const float inv = 1.f / fmaxf(zs, 1e-30f);
    gvec_s[c][4 * h + 0] = acc.x * inv;
    gvec_s[c][4 * h + 1] = acc.y * inv;
    gvec_s[c][4 * h + 2] = acc.z * inv;
    gvec_s[c][4 * h + 3] = acc.w * inv;   // empty cat: 0 * 1e30 = 0
  }
  __syncthreads();

  // ---- top-level attention ----
  if (t < CC * HH) {
    int cc = t / HH, j = t % HH;
    const float* wp = &Wt1[(size_t)j * (2 * DD)];
    float a = bt1[j];
    #pragma unroll 8
    for (int d = 0; d < DD; ++d) a += wp[d] * u_s[d];
    #pragma unroll 8
    for (int d = 0; d < DD; ++d) a += wp[DD + d] * gvec_s[cc][d];
    h2_s[cc][j] = fmaxf(a, 0.f);
  }
  __syncthreads();

  if (t == 0) {
    float s2[CC];
    float m = -INFINITY;
    #pragma unroll
    for (int cc = 0; cc < CC; ++cc) {
      float a = bt2[0];
      #pragma unroll
      for (int j = 0; j < HH; ++j) a += Wt2[j] * h2_s[cc][j];
      s2[cc] = a;
      if (cnt_s[cc] > 0) m = fmaxf(m, a);
    }
    if (m == -INFINITY) m = 0.f;
    float sum = 0.f;
    float z2[CC];
    #pragma unroll
    for (int cc = 0; cc < CC; ++cc) {
      z2[cc] = (cnt_s[cc] > 0) ? expf(s2[cc] - m) : 0.f;
      sum += z2[cc];
    }
    float inv = 1.f / fmaxf(sum, 1e-30f);
    #pragma unroll
    for (int cc = 0; cc < CC; ++cc) w2_s[cc] = z2[cc] * inv;
  }
  __syncthreads();

  if (t < DD) {
    float hy = 0.f;
    #pragma unroll
    for (int cc = 0; cc < CC; ++cc) hy += w2_s[cc] * gvec_s[cc][t];
    float ti = item_emb[(size_t)item_inputs[b] * DD + t];
    float prod = hy * ti;
    #pragma unroll
    for (int off = 32; off > 0; off >>= 1)
      prod += __shfl_down(prod, off, 64);
    if (t == 0) out[b] = prod;
  }
}

extern "C" void kernel_launch(void* const* d_in, const int* in_sizes, int n_in,
                              void* d_out, int out_size, void* d_ws, size_t ws_size,
                              hipStream_t stream) {
  const int*   user_inputs   = (const int*)d_in[0];
  const int*   record_inputs = (const int*)d_in[1];
  const int*   item_inputs   = (const int*)d_in[2];
  const int*   item_cat      = (const int*)d_in[3];
  const float* user_emb      = (const float*)d_in[4];
  const float* item_emb      = (const float*)d_in[5];
  const float* W1            = (const float*)d_in[6];
  const float* b1            = (const float*)d_in[7];
  const float* W2            = (const float*)d_in[8];
  const float* b2            = (const float*)d_in[9];
  const float* Wt1           = (const float*)d_in[10];
  const float* bt1           = (const float*)d_in[11];
  const float* Wt2           = (const float*)d_in[12];
  const float* bt2           = (const float*)d_in[13];
  float* out = (float*)d_out;

  char* ws = (char*)d_ws;
  int*   srow_g   = (int*)(ws);                 // B*PADL ints
  float* z_g      = (float*)(ws + 2097152);     // B*PADL floats
  int*   cstart_g = (int*)(ws + 4194304);       // B*20 ints
  float* pre_g    = (float*)(ws + 4358144);     // B*C*H floats

  din_ka<<<NB, 256, 0, stream>>>(user_inputs, record_inputs, item_cat,
                                 user_emb, W1, b1, srow_g, cstart_g, pre_g);
  din_kb<<<(NB * 64) / 256, 256, 0, stream>>>(item_emb, W1, W2, b2,
                                              srow_g, cstart_g, pre_g, z_g);
  din_kcd<<<NB, 576, 0, stream>>>(user_inputs, item_inputs, user_emb, item_emb,
                                  Wt1, bt1, Wt2, bt2,
                                  srow_g, z_g, cstart_g, out);
}

// Round 12
// 80.807 us; speedup vs baseline: 1.0338x; 1.0338x over previous
//
#include <hip/hip_runtime.h>
#include <math.h>

#define NB 2048
#define LL 200
#define PADL 256   // padded per-user slot stride (max needed 200+9*3=227)
#define DD 64
#define CC 9
#define HH 16
#define NW 4

// ---- d_ws layout (bytes) ----
// srow_g : int  [B*PADL]  @ 0          (2,097,152)
// z_g    : float[B*PADL]  @ 2,097,152  (2,097,152)
// cstart : int  [B*20]    @ 4,194,304  (163,840)  [0..9]=padded starts(+total@9), [10..18]=counts
// pre_g  : float[B*C*H]   @ 4,358,144  (1,179,648)  -- aliased by gvec_g
// gvec_g : float[B*C*D]   @ 4,358,144  (4,718,592)  (kb reads pre before kc writes gvec)

// kA: per-user ballot sort (4-aligned padded groups) + pre = b1 + W1u.u
__global__ __launch_bounds__(256) void din_ka(
    const int* __restrict__ user_inputs,
    const int* __restrict__ record_inputs,
    const int* __restrict__ item_cat,
    const float* __restrict__ user_emb,
    const float* __restrict__ W1,
    const float* __restrict__ b1,
    int* __restrict__ srow_g,
    int* __restrict__ cstart_g,
    float* __restrict__ pre_g)
{
  const int b = blockIdx.x;
  const int t = threadIdx.x;
  const int wave = t >> 6, lane = t & 63;

  __shared__ float u_s[DD];
  __shared__ int   wcnt[NW][CC];
  __shared__ int   cstart[CC + 1];
  __shared__ int   ccnt[CC];

  int r = -1, c0 = -1;
  if (t < LL) {
    r = record_inputs[b * LL + t];
    if (r >= 0) c0 = item_cat[r];
  }
  if (t < DD) u_s[t] = user_emb[(size_t)user_inputs[b] * DD + t];

  srow_g[b * PADL + t] = 0;   // pad slots -> row 0 (valid memory, zero weight)

  int myrank = 0;
  #pragma unroll
  for (int c = 0; c < CC; ++c) {
    unsigned long long m = __ballot(c0 == c);
    if (lane == 0) wcnt[wave][c] = __popcll(m);
    if (c0 == c) myrank = __popcll(m & ((1ULL << lane) - 1ULL));
  }
  __syncthreads();

  if (t == 0) {
    int acc = 0;
    #pragma unroll
    for (int c = 0; c < CC; ++c) {
      cstart[c] = acc;
      int cn = wcnt[0][c] + wcnt[1][c] + wcnt[2][c] + wcnt[3][c];
      ccnt[c] = cn;
      acc = (acc + cn + 3) & ~3;   // 4-aligned next group
    }
    cstart[CC] = acc;
  }
  if (t < CC * HH) {   // pre = b1 + W1u . u  -> global
    int c = t / HH, j = t % HH;
    const float* wp = &W1[(size_t)(c * HH + j) * (2 * DD)];
    float acc = b1[c * HH + j];
    #pragma unroll 8
    for (int d = 0; d < DD; ++d) acc += wp[d] * u_s[d];
    pre_g[(size_t)(b * CC + c) * HH + j] = acc;
  }
  __syncthreads();

  if (c0 >= 0) {
    int off = cstart[c0];
    for (int w = 0; w < wave; ++w) off += wcnt[w][c0];
    srow_g[b * PADL + off + myrank] = r;
  }
  if (t < CC + 1) cstart_g[b * 20 + t] = cstart[t];
  else if (t < 2 * CC + 1) cstart_g[b * 20 + 10 + (t - CC - 1)] = ccnt[t - CC - 1];
}

// kB: 4 same-category items per thread; W1 e-half in LDS [ji][c].
__global__ __launch_bounds__(256) void din_kb(
    const float* __restrict__ item_emb,
    const float* __restrict__ W1,
    const float* __restrict__ W2,
    const float* __restrict__ b2,
    const int* __restrict__ srow_g,
    const int* __restrict__ cstart_g,
    const float* __restrict__ pre_g,
    float* __restrict__ z_g)
{
  const int t = threadIdx.x;

  __shared__ float4 w_lds[HH * 16 * CC];   // 36.9 KB
  __shared__ float  w2_s[CC * HH];
  __shared__ float  b2_s[CC];

  #pragma unroll
  for (int k = t; k < HH * 16 * CC; k += 256) {
    int c = k >> 8;
    int ji = k & 255;
    int j = ji >> 4, i = ji & 15;
    w_lds[ji * CC + c] = ((const float4*)W1)[(size_t)(c * HH + j) * 32 + 16 + i];
  }
  if (t < CC * HH) w2_s[t] = W2[t];
  if (t < CC) b2_s[t] = b2[t];
  __syncthreads();

  const int g = blockIdx.x * 256 + t;      // [0, B*64): one thread = 4 slots
  const int b = g >> 6;
  const int q4 = (g & 63) * 4;             // base slot (4-aligned)
  const int* cs = &cstart_g[b * 20];
  if (q4 >= cs[CC]) return;                // beyond padded total

  int c = 0;
  #pragma unroll
  for (int q = 0; q < CC - 1; ++q) c += (q4 >= cs[q + 1]) ? 1 : 0;

  const int base = b * PADL + q4;
  const int r0 = srow_g[base + 0], r1 = srow_g[base + 1];
  const int r2 = srow_g[base + 2], r3 = srow_g[base + 3];
  const float4* e0 = (const float4*)&item_emb[(size_t)r0 * DD];
  const float4* e1 = (const float4*)&item_emb[(size_t)r1 * DD];
  const float4* e2 = (const float4*)&item_emb[(size_t)r2 * DD];
  const float4* e3 = (const float4*)&item_emb[(size_t)r3 * DD];

  float acc0[HH], acc1[HH], acc2[HH], acc3[HH];
  {
    const float4* pp = (const float4*)&pre_g[(size_t)(b * CC + c) * HH];
    #pragma unroll
    for (int jq = 0; jq < 4; ++jq) {
      float4 pv = pp[jq];
      acc0[jq*4+0] = pv.x; acc0[jq*4+1] = pv.y; acc0[jq*4+2] = pv.z; acc0[jq*4+3] = pv.w;
      acc1[jq*4+0] = pv.x; acc1[jq*4+1] = pv.y; acc1[jq*4+2] = pv.z; acc1[jq*4+3] = pv.w;
      acc2[jq*4+0] = pv.x; acc2[jq*4+1] = pv.y; acc2[jq*4+2] = pv.z; acc2[jq*4+3] = pv.w;
      acc3[jq*4+0] = pv.x; acc3[jq*4+1] = pv.y; acc3[jq*4+2] = pv.z; acc3[jq*4+3] = pv.w;
    }
  }

  #pragma unroll
  for (int i = 0; i < 16; ++i) {
    float4 a0 = e0[i], a1 = e1[i], a2 = e2[i], a3 = e3[i];
    #pragma unroll
    for (int j = 0; j < HH; ++j) {
      float4 wv = w_lds[(j * 16 + i) * CC + c];
      acc0[j] += wv.x * a0.x + wv.y * a0.y + wv.z * a0.z + wv.w * a0.w;
      acc1[j] += wv.x * a1.x + wv.y * a1.y + wv.z * a1.z + wv.w * a1.w;
      acc2[j] += wv.x * a2.x + wv.y * a2.y + wv.z * a2.z + wv.w * a2.w;
      acc3[j] += wv.x * a3.x + wv.y * a3.y + wv.z * a3.z + wv.w * a3.w;
    }
  }

  float s0 = b2_s[c], s1 = s0, s2 = s0, s3 = s0;
  #pragma unroll
  for (int j = 0; j < HH; ++j) {
    float w2v = w2_s[c * HH + j];
    s0 += w2v * fmaxf(acc0[j], 0.f);
    s1 += w2v * fmaxf(acc1[j], 0.f);
    s2 += w2v * fmaxf(acc2[j], 0.f);
    s3 += w2v * fmaxf(acc3[j], 0.f);
  }
  *(float4*)&z_g[base] = make_float4(expf(s0), expf(s1), expf(s2), expf(s3));
}

// kC: one wave per (b,c), barrier-free, float4 lanes (16 lanes x float4 = 1 row,
// 4 rows per wave-instruction). srow/z preloaded to regs -> all e-loads independent.
__global__ __launch_bounds__(256) void din_kc(
    const float* __restrict__ item_emb,
    const int* __restrict__ srow_g,
    const float* __restrict__ z_g,
    const int* __restrict__ cstart_g,
    float* __restrict__ gvec_g)
{
  const int pair = blockIdx.x * NW + (threadIdx.x >> 6);   // [0, B*C)
  const int lane = threadIdx.x & 63;
  const int b = pair / CC;
  const int c = pair - b * CC;
  const int g = lane >> 4;         // item subgroup 0..3
  const int h = lane & 15;         // d-quad (d = 4h..4h+3)

  const int i0 = cstart_g[b * 20 + c];
  const int n  = cstart_g[b * 20 + 10 + c];
  const int sb = b * PADL + i0;

  float4 acc = make_float4(0.f, 0.f, 0.f, 0.f);
  float  zs  = 0.f;

  for (int cb = 0; cb < n; cb += 64) {
    const int nn = min(64, n - cb);
    const bool ok = (cb + lane) < n;
    int   rv = ok ? srow_g[sb + cb + lane] : 0;   // one coalesced load / chunk
    float zv = ok ? z_g[sb + cb + lane]    : 0.f;
    zs += zv;

    const int kmax = (nn + 3) >> 2;
    #pragma unroll 4
    for (int k = 0; k < kmax; ++k) {
      const int j = 4 * k + g;                    // j <= nn+2 <= 63
      const int   rr = __shfl(rv, j, 64);
      const float zz = __shfl(zv, j, 64);         // 0 for pad items
      const float4 ev = *(const float4*)&item_emb[(size_t)rr * DD + 4 * h];
      acc.x += zz * ev.x; acc.y += zz * ev.y;
      acc.z += zz * ev.z; acc.w += zz * ev.w;
    }
  }

  // combine the 4 item-subgroups (butterfly over lane bits 4,5)
  acc.x += __shfl_xor(acc.x, 16, 64); acc.y += __shfl_xor(acc.y, 16, 64);
  acc.z += __shfl_xor(acc.z, 16, 64); acc.w += __shfl_xor(acc.w, 16, 64);
  acc.x += __shfl_xor(acc.x, 32, 64); acc.y += __shfl_xor(acc.y, 32, 64);
  acc.z += __shfl_xor(acc.z, 32, 64); acc.w += __shfl_xor(acc.w, 32, 64);
  #pragma unroll
  for (int off = 32; off > 0; off >>= 1) zs += __shfl_xor(zs, off, 64);

  if (g == 0) {
    const float inv = 1.f / fmaxf(zs, 1e-30f);
    *(float4*)&gvec_g[(size_t)pair * DD + 4 * h] =
        make_float4(acc.x * inv, acc.y * inv, acc.z * inv, acc.w * inv);
  }
}

// kD: per-user top-level attention + output
__global__ __launch_bounds__(256) void din_kd(
    const int* __restrict__ user_inputs,
    const int* __restrict__ item_inputs,
    const float* __restrict__ user_emb,
    const float* __restrict__ item_emb,
    const float* __restrict__ Wt1,
    const float* __restrict__ bt1,
    const float* __restrict__ Wt2,
    const float* __restrict__ bt2,
    const int* __restrict__ cstart_g,
    const float* __restrict__ gvec_g,
    float* __restrict__ out)
{
  const int b = blockIdx.x;
  const int t = threadIdx.x;

  __shared__ float u_s[DD];
  __shared__ float g_s[CC * DD];
  __shared__ float h2_s[CC][HH];
  __shared__ float w2_s[CC];
  __shared__ int   cnt_s[CC];

  if (t < DD) u_s[t] = user_emb[(size_t)user_inputs[b] * DD + t];
  for (int x = t; x < CC * DD; x += 256) g_s[x] = gvec_g[(size_t)b * CC * DD + x];
  if (t < CC) cnt_s[t] = cstart_g[b * 20 + 10 + t];
  __syncthreads();

  if (t < CC * HH) {
    int c = t / HH, j = t % HH;
    const float* wp = &Wt1[(size_t)j * (2 * DD)];
    float acc = bt1[j];
    #pragma unroll 8
    for (int d = 0; d < DD; ++d) acc += wp[d] * u_s[d];
    #pragma unroll 8
    for (int d = 0; d < DD; ++d) acc += wp[DD + d] * g_s[c * DD + d];
    h2_s[c][j] = fmaxf(acc, 0.f);
  }
  __syncthreads();

  if (t == 0) {
    float s2[CC];
    float m = -INFINITY;
    #pragma unroll
    for (int c = 0; c < CC; ++c) {
      float acc = bt2[0];
      #pragma unroll
      for (int j = 0; j < HH; ++j) acc += Wt2[j] * h2_s[c][j];
      s2[c] = acc;
      if (cnt_s[c] > 0) m = fmaxf(m, acc);
    }
    if (m == -INFINITY) m = 0.f;
    float sum = 0.f;
    float z2[CC];
    #pragma unroll
    for (int c = 0; c < CC; ++c) {
      z2[c] = (cnt_s[c] > 0) ? expf(s2[c] - m) : 0.f;
      sum += z2[c];
    }
    float inv = 1.f / fmaxf(sum, 1e-30f);
    #pragma unroll
    for (int c = 0; c < CC; ++c) w2_s[c] = z2[c] * inv;
  }
  __syncthreads();

  if (t < DD) {
    float hy = 0.f;
    #pragma unroll
    for (int c = 0; c < CC; ++c) hy += w2_s[c] * g_s[c * DD + t];
    float ti = item_emb[(size_t)item_inputs[b] * DD + t];
    float prod = hy * ti;
    #pragma unroll
    for (int off = 32; off > 0; off >>= 1)
      prod += __shfl_down(prod, off, 64);
    if (t == 0) out[b] = prod;
  }
}

extern "C" void kernel_launch(void* const* d_in, const int* in_sizes, int n_in,
                              void* d_out, int out_size, void* d_ws, size_t ws_size,
                              hipStream_t stream) {
  const int*   user_inputs   = (const int*)d_in[0];
  const int*   record_inputs = (const int*)d_in[1];
  const int*   item_inputs   = (const int*)d_in[2];
  const int*   item_cat      = (const int*)d_in[3];
  const float* user_emb      = (const float*)d_in[4];
  const float* item_emb      = (const float*)d_in[5];
  const float* W1            = (const float*)d_in[6];
  const float* b1            = (const float*)d_in[7];
  const float* W2            = (const float*)d_in[8];
  const float* b2            = (const float*)d_in[9];
  const float* Wt1           = (const float*)d_in[10];
  const float* bt1           = (const float*)d_in[11];
  const float* Wt2           = (const float*)d_in[12];
  const float* bt2           = (const float*)d_in[13];
  float* out = (float*)d_out;

  char* ws = (char*)d_ws;
  int*   srow_g   = (int*)(ws);                 // B*PADL ints
  float* z_g      = (float*)(ws + 2097152);     // B*PADL floats
  int*   cstart_g = (int*)(ws + 4194304);       // B*20 ints
  float* pre_g    = (float*)(ws + 4358144);     // B*C*H floats (aliased below)
  float* gvec_g   = (float*)(ws + 4358144);     // B*C*D floats (written after pre consumed)

  din_ka<<<NB, 256, 0, stream>>>(user_inputs, record_inputs, item_cat,
                                 user_emb, W1, b1, srow_g, cstart_g, pre_g);
  din_kb<<<(NB * 64) / 256, 256, 0, stream>>>(item_emb, W1, W2, b2,
                                              srow_g, cstart_g, pre_g, z_g);
  din_kc<<<(NB * CC) / NW, 256, 0, stream>>>(item_emb, srow_g, z_g, cstart_g, gvec_g);
  din_kd<<<NB, 256, 0, stream>>>(user_inputs, item_inputs, user_emb, item_emb,
                                 Wt1, bt1, Wt2, bt2, cstart_g, gvec_g, out);
}

// Round 13
// 79.554 us; speedup vs baseline: 1.0500x; 1.0157x over previous
//
#include <hip/hip_runtime.h>
#include <math.h>

#define NB 2048
#define LL 200
#define PADL 256   // padded per-user slot stride
#define DD 64
#define CC 9
#define HH 16
#define NW 4

// ---- d_ws layout (bytes) ----
// srow_g : int  [B*PADL]  @ 0          (2,097,152)
// pre_g  : float[B*C*H]   @ 2,097,152  (1,179,648)
// cstart : int  [B*20]    @ 4,194,304  (163,840)  [0..9]=padded starts(+total@9), [10..18]=counts
// gvec_g : float[B*C*D]   @ 4,358,144  (4,718,592)

// kA: per-user ballot sort (4-aligned padded groups) + pre = b1 + W1u.u
__global__ __launch_bounds__(256) void din_ka(
    const int* __restrict__ user_inputs,
    const int* __restrict__ record_inputs,
    const int* __restrict__ item_cat,
    const float* __restrict__ user_emb,
    const float* __restrict__ W1,
    const float* __restrict__ b1,
    int* __restrict__ srow_g,
    int* __restrict__ cstart_g,
    float* __restrict__ pre_g)
{
  const int b = blockIdx.x;
  const int t = threadIdx.x;
  const int wave = t >> 6, lane = t & 63;

  __shared__ float u_s[DD];
  __shared__ int   wcnt[NW][CC];
  __shared__ int   cstart[CC + 1];
  __shared__ int   ccnt[CC];

  int r = -1, c0 = -1;
  if (t < LL) {
    r = record_inputs[b * LL + t];
    if (r >= 0) c0 = item_cat[r];
  }
  if (t < DD) u_s[t] = user_emb[(size_t)user_inputs[b] * DD + t];

  srow_g[b * PADL + t] = 0;   // pad slots -> row 0 (valid memory, zero weight)

  int myrank = 0;
  #pragma unroll
  for (int c = 0; c < CC; ++c) {
    unsigned long long m = __ballot(c0 == c);
    if (lane == 0) wcnt[wave][c] = __popcll(m);
    if (c0 == c) myrank = __popcll(m & ((1ULL << lane) - 1ULL));
  }
  __syncthreads();

  if (t == 0) {
    int acc = 0;
    #pragma unroll
    for (int c = 0; c < CC; ++c) {
      cstart[c] = acc;
      int cn = wcnt[0][c] + wcnt[1][c] + wcnt[2][c] + wcnt[3][c];
      ccnt[c] = cn;
      acc = (acc + cn + 3) & ~3;   // 4-aligned next group
    }
    cstart[CC] = acc;
  }
  if (t < CC * HH) {   // pre = b1 + W1u . u  -> global
    int c = t / HH, j = t % HH;
    const float* wp = &W1[(size_t)(c * HH + j) * (2 * DD)];
    float acc = b1[c * HH + j];
    #pragma unroll 8
    for (int d = 0; d < DD; ++d) acc += wp[d] * u_s[d];
    pre_g[(size_t)(b * CC + c) * HH + j] = acc;
  }
  __syncthreads();

  if (c0 >= 0) {
    int off = cstart[c0];
    for (int w = 0; w < wave; ++w) off += wcnt[w][c0];
    srow_g[b * PADL + off + myrank] = r;
  }
  if (t < CC + 1) cstart_g[b * 20 + t] = cstart[t];
  else if (t < 2 * CC + 1) cstart_g[b * 20 + 10 + (t - CC - 1)] = ccnt[t - CC - 1];
}

// kBC: fused score + gvec. One wave per (b,c). Lane (g,h): item-subgroup g (0..3),
// d-quad h (0..15). W1 e-half held in 64 registers (wave-uniform c). Each e-row is
// loaded ONCE (coalesced) and used for both the MLP score and the z.e accumulation.
__global__ __launch_bounds__(256) void din_kbc(
    const float* __restrict__ item_emb,
    const float* __restrict__ W1,
    const float* __restrict__ W2,
    const float* __restrict__ b2,
    const int* __restrict__ srow_g,
    const int* __restrict__ cstart_g,
    const float* __restrict__ pre_g,
    float* __restrict__ gvec_g)
{
  const int pair = blockIdx.x * NW + (threadIdx.x >> 6);   // [0, B*C)
  const int lane = threadIdx.x & 63;
  const int g = lane >> 4;        // item subgroup
  const int h = lane & 15;        // d-quad (d = 4h..4h+3)
  const int b = pair / CC;
  const int c = pair - b * CC;

  const int i0 = cstart_g[b * 20 + c];
  const int n  = cstart_g[b * 20 + 10 + c];
  const int sb = b * PADL + i0;

  // W1 e-half column slice for this category: Wj[j] = W1[c][j][64+4h .. 64+4h+3]
  float4 Wj[HH];
  #pragma unroll
  for (int j = 0; j < HH; ++j)
    Wj[j] = *(const float4*)&W1[(size_t)(c * HH + j) * (2 * DD) + DD + 4 * h];

  const float pre_h = pre_g[(size_t)(b * CC + c) * HH + h];
  const float w2h   = W2[c * HH + h];
  const float b2c   = b2[c];

  float4 acc = make_float4(0.f, 0.f, 0.f, 0.f);
  float  zs  = 0.f;

  for (int k = 0; k < n; k += 4) {
    const int i = k + g;                        // may reach n+3 (pad slots, row 0)
    const int rr = srow_g[sb + i];
    const float4 e = *(const float4*)&item_emb[(size_t)rr * DD + 4 * h];

    // per-quad partials for all 16 hidden units
    float p[HH];
    #pragma unroll
    for (int j = 0; j < HH; ++j)
      p[j] = Wj[j].x * e.x + Wj[j].y * e.y + Wj[j].z * e.z + Wj[j].w * e.w;

    // reduce-scatter butterfly over the 16 h-lanes: lane h ends with h_{j=h}
    float q8[8];
    #pragma unroll
    for (int j = 0; j < 8; ++j) {
      float keep = (h & 8) ? p[j + 8] : p[j];
      float send = (h & 8) ? p[j]     : p[j + 8];
      q8[j] = keep + __shfl_xor(send, 8, 64);
    }
    float q4v[4];
    #pragma unroll
    for (int j = 0; j < 4; ++j) {
      float keep = (h & 4) ? q8[j + 4] : q8[j];
      float send = (h & 4) ? q8[j]     : q8[j + 4];
      q4v[j] = keep + __shfl_xor(send, 4, 64);
    }
    float q2v[2];
    #pragma unroll
    for (int j = 0; j < 2; ++j) {
      float keep = (h & 2) ? q4v[j + 2] : q4v[j];
      float send = (h & 2) ? q4v[j]     : q4v[j + 2];
      q2v[j] = keep + __shfl_xor(send, 2, 64);
    }
    float q1;
    {
      float keep = (h & 1) ? q2v[1] : q2v[0];
      float send = (h & 1) ? q2v[0] : q2v[1];
      q1 = keep + __shfl_xor(send, 1, 64);
    }

    // s = b2 + sum_j w2[j] * relu(pre[j] + hj)
    float v = w2h * fmaxf(q1 + pre_h, 0.f);
    v += __shfl_xor(v, 1, 64);
    v += __shfl_xor(v, 2, 64);
    v += __shfl_xor(v, 4, 64);
    v += __shfl_xor(v, 8, 64);

    const float z = (i < n) ? expf(v + b2c) : 0.f;   // pad items contribute 0
    acc.x += z * e.x; acc.y += z * e.y; acc.z += z * e.z; acc.w += z * e.w;
    zs += z;
  }

  // combine the 4 item-subgroups (butterfly over lane bits 4,5)
  acc.x += __shfl_xor(acc.x, 16, 64); acc.y += __shfl_xor(acc.y, 16, 64);
  acc.z += __shfl_xor(acc.z, 16, 64); acc.w += __shfl_xor(acc.w, 16, 64);
  acc.x += __shfl_xor(acc.x, 32, 64); acc.y += __shfl_xor(acc.y, 32, 64);
  acc.z += __shfl_xor(acc.z, 32, 64); acc.w += __shfl_xor(acc.w, 32, 64);
  zs += __shfl_xor(zs, 16, 64);
  zs += __shfl_xor(zs, 32, 64);

  if (g == 0) {
    const float inv = 1.f / fmaxf(zs, 1e-30f);
    *(float4*)&gvec_g[(size_t)pair * DD + 4 * h] =
        make_float4(acc.x * inv, acc.y * inv, acc.z * inv, acc.w * inv);
  }
}

// kD: per-user top-level attention + output
__global__ __launch_bounds__(256) void din_kd(
    const int* __restrict__ user_inputs,
    const int* __restrict__ item_inputs,
    const float* __restrict__ user_emb,
    const float* __restrict__ item_emb,
    const float* __restrict__ Wt1,
    const float* __restrict__ bt1,
    const float* __restrict__ Wt2,
    const float* __restrict__ bt2,
    const int* __restrict__ cstart_g,
    const float* __restrict__ gvec_g,
    float* __restrict__ out)
{
  const int b = blockIdx.x;
  const int t = threadIdx.x;

  __shared__ float u_s[DD];
  __shared__ float g_s[CC * DD];
  __shared__ float h2_s[CC][HH];
  __shared__ float w2_s[CC];
  __shared__ int   cnt_s[CC];

  if (t < DD) u_s[t] = user_emb[(size_t)user_inputs[b] * DD + t];
  for (int x = t; x < CC * DD; x += 256) g_s[x] = gvec_g[(size_t)b * CC * DD + x];
  if (t < CC) cnt_s[t] = cstart_g[b * 20 + 10 + t];
  __syncthreads();

  if (t < CC * HH) {
    int c = t / HH, j = t % HH;
    const float* wp = &Wt1[(size_t)j * (2 * DD)];
    float acc = bt1[j];
    #pragma unroll 8
    for (int d = 0; d < DD; ++d) acc += wp[d] * u_s[d];
    #pragma unroll 8
    for (int d = 0; d < DD; ++d) acc += wp[DD + d] * g_s[c * DD + d];
    h2_s[c][j] = fmaxf(acc, 0.f);
  }
  __syncthreads();

  if (t == 0) {
    float s2[CC];
    float m = -INFINITY;
    #pragma unroll
    for (int c = 0; c < CC; ++c) {
      float acc = bt2[0];
      #pragma unroll
      for (int j = 0; j < HH; ++j) acc += Wt2[j] * h2_s[c][j];
      s2[c] = acc;
      if (cnt_s[c] > 0) m = fmaxf(m, acc);
    }
    if (m == -INFINITY) m = 0.f;
    float sum = 0.f;
    float z2[CC];
    #pragma unroll
    for (int c = 0; c < CC; ++c) {
      z2[c] = (cnt_s[c] > 0) ? expf(s2[c] - m) : 0.f;
      sum += z2[c];
    }
    float inv = 1.f / fmaxf(sum, 1e-30f);
    #pragma unroll
    for (int c = 0; c < CC; ++c) w2_s[c] = z2[c] * inv;
  }
  __syncthreads();

  if (t < DD) {
    float hy = 0.f;
    #pragma unroll
    for (int c = 0; c < CC; ++c) hy += w2_s[c] * g_s[c * DD + t];
    float ti = item_emb[(size_t)item_inputs[b] * DD + t];
    float prod = hy * ti;
    #pragma unroll
    for (int off = 32; off > 0; off >>= 1)
      prod += __shfl_down(prod, off, 64);
    if (t == 0) out[b] = prod;
  }
}

extern "C" void kernel_launch(void* const* d_in, const int* in_sizes, int n_in,
                              void* d_out, int out_size, void* d_ws, size_t ws_size,
                              hipStream_t stream) {
  const int*   user_inputs   = (const int*)d_in[0];
  const int*   record_inputs = (const int*)d_in[1];
  const int*   item_inputs   = (const int*)d_in[2];
  const int*   item_cat      = (const int*)d_in[3];
  const float* user_emb      = (const float*)d_in[4];
  const float* item_emb      = (const float*)d_in[5];
  const float* W1            = (const float*)d_in[6];
  const float* b1            = (const float*)d_in[7];
  const float* W2            = (const float*)d_in[8];
  const float* b2            = (const float*)d_in[9];
  const float* Wt1           = (const float*)d_in[10];
  const float* bt1           = (const float*)d_in[11];
  const float* Wt2           = (const float*)d_in[12];
  const float* bt2           = (const float*)d_in[13];
  float* out = (float*)d_out;

  char* ws = (char*)d_ws;
  int*   srow_g   = (int*)(ws);                 // B*PADL ints
  float* pre_g    = (float*)(ws + 2097152);     // B*C*H floats
  int*   cstart_g = (int*)(ws + 4194304);       // B*20 ints
  float* gvec_g   = (float*)(ws + 4358144);     // B*C*D floats

  din_ka<<<NB, 256, 0, stream>>>(user_inputs, record_inputs, item_cat,
                                 user_emb, W1, b1, srow_g, cstart_g, pre_g);
  din_kbc<<<(NB * CC) / NW, 256, 0, stream>>>(item_emb, W1, W2, b2,
                                              srow_g, cstart_g, pre_g, gvec_g);
  din_kd<<<NB, 256, 0, stream>>>(user_inputs, item_inputs, user_emb, item_emb,
                                 Wt1, bt1, Wt2, bt2, cstart_g, gvec_g, out);
}

// Round 15
// 78.845 us; speedup vs baseline: 1.0595x; 1.0090x over previous
//
#include <hip/hip_runtime.h>
#include <math.h>

#define NB 2048
#define LL 200
#define PADL 256   // padded per-user slot stride
#define DD 64
#define CC 9
#define HH 16
#define NW 4

// ---- d_ws layout (bytes) ----
// srow_g : int  [B*PADL]  @ 0          (2,097,152)
// z_g    : float[B*PADL]  @ 2,097,152  (2,097,152)
// cstart : int  [B*20]    @ 4,194,304  (163,840)  [0..9]=padded starts(+total@9), [10..18]=counts
// pre_g  : float[B*C*H]   @ 4,358,144  (1,179,648)

// kA: per-user ballot sort (4-aligned padded groups) + pre = b1 + W1u.u
__global__ __launch_bounds__(256) void din_ka(
    const int* __restrict__ user_inputs,
    const int* __restrict__ record_inputs,
    const int* __restrict__ item_cat,
    const float* __restrict__ user_emb,
    const float* __restrict__ W1,
    const float* __restrict__ b1,
    int* __restrict__ srow_g,
    int* __restrict__ cstart_g,
    float* __restrict__ pre_g)
{
  const int b = blockIdx.x;
  const int t = threadIdx.x;
  const int wave = t >> 6, lane = t & 63;

  __shared__ float u_s[DD];
  __shared__ int   wcnt[NW][CC];
  __shared__ int   cstart[CC + 1];
  __shared__ int   ccnt[CC];

  int r = -1, c0 = -1;
  if (t < LL) {
    r = record_inputs[b * LL + t];
    if (r >= 0) c0 = item_cat[r];
  }
  if (t < DD) u_s[t] = user_emb[(size_t)user_inputs[b] * DD + t];

  srow_g[b * PADL + t] = 0;   // pad slots -> row 0 (valid memory, zero weight)

  int myrank = 0;
  #pragma unroll
  for (int c = 0; c < CC; ++c) {
    unsigned long long m = __ballot(c0 == c);
    if (lane == 0) wcnt[wave][c] = __popcll(m);
    if (c0 == c) myrank = __popcll(m & ((1ULL << lane) - 1ULL));
  }
  __syncthreads();

  if (t == 0) {
    int acc = 0;
    #pragma unroll
    for (int c = 0; c < CC; ++c) {
      cstart[c] = acc;
      int cn = wcnt[0][c] + wcnt[1][c] + wcnt[2][c] + wcnt[3][c];
      ccnt[c] = cn;
      acc = (acc + cn + 3) & ~3;   // 4-aligned next group
    }
    cstart[CC] = acc;
  }
  if (t < CC * HH) {   // pre = b1 + W1u . u  -> global
    int c = t / HH, j = t % HH;
    const float* wp = &W1[(size_t)(c * HH + j) * (2 * DD)];
    float acc = b1[c * HH + j];
    #pragma unroll 8
    for (int d = 0; d < DD; ++d) acc += wp[d] * u_s[d];
    pre_g[(size_t)(b * CC + c) * HH + j] = acc;
  }
  __syncthreads();

  if (c0 >= 0) {
    int off = cstart[c0];
    for (int w = 0; w < wave; ++w) off += wcnt[w][c0];
    srow_g[b * PADL + off + myrank] = r;
  }
  if (t < CC + 1) cstart_g[b * 20 + t] = cstart[t];
  else if (t < 2 * CC + 1) cstart_g[b * 20 + 10 + (t - CC - 1)] = ccnt[t - CC - 1];
}

// kB-v2: thread pair (group, jh) scores 4 same-category items for 8 hidden units
// each; combine j-halves with one shfl_xor. W1 e-half in LDS [ji][c].
__global__ __launch_bounds__(256) void din_kb(
    const float* __restrict__ item_emb,
    const float* __restrict__ W1,
    const float* __restrict__ W2,
    const float* __restrict__ b2,
    const int* __restrict__ srow_g,
    const int* __restrict__ cstart_g,
    const float* __restrict__ pre_g,
    float* __restrict__ z_g)
{
  const int t = threadIdx.x;

  __shared__ float4 w_lds[HH * 16 * CC];   // 36.9 KB, [j*16+i][c]
  __shared__ float  w2_s[CC * HH];
  __shared__ float  b2_s[CC];

  #pragma unroll
  for (int k = t; k < HH * 16 * CC; k += 256) {
    int c = k >> 8;
    int ji = k & 255;
    int j = ji >> 4, i = ji & 15;
    w_lds[ji * CC + c] = ((const float4*)W1)[(size_t)(c * HH + j) * 32 + 16 + i];
  }
  if (t < CC * HH) w2_s[t] = W2[t];
  if (t < CC) b2_s[t] = b2[t];
  __syncthreads();

  const int gid = blockIdx.x * 256 + t;    // [0, B*128)
  const int b   = gid >> 7;                // 2 users per block
  const int pt  = gid & 127;
  const int grp = pt >> 1;                 // item group 0..63
  const int jh  = pt & 1;                  // j-half
  const int q4  = grp * 4;
  const int* cs = &cstart_g[b * 20];
  if (q4 >= cs[CC]) return;                // pair-uniform exit (both jh lanes)

  int c = 0;
  #pragma unroll
  for (int q = 0; q < CC - 1; ++q) c += (q4 >= cs[q + 1]) ? 1 : 0;

  const int base = b * PADL + q4;
  const int r0 = srow_g[base + 0], r1 = srow_g[base + 1];
  const int r2 = srow_g[base + 2], r3 = srow_g[base + 3];
  const float4* e0 = (const float4*)&item_emb[(size_t)r0 * DD];
  const float4* e1 = (const float4*)&item_emb[(size_t)r1 * DD];
  const float4* e2 = (const float4*)&item_emb[(size_t)r2 * DD];
  const float4* e3 = (const float4*)&item_emb[(size_t)r3 * DD];

  float acc0[8], acc1[8], acc2[8], acc3[8];
  {
    const float* pp = &pre_g[(size_t)(b * CC + c) * HH + jh * 8];
    #pragma unroll
    for (int jj = 0; jj < 8; ++jj) {
      float pv = pp[jj];
      acc0[jj] = pv; acc1[jj] = pv; acc2[jj] = pv; acc3[jj] = pv;
    }
  }

  #pragma unroll
  for (int i = 0; i < 16; ++i) {
    float4 a0 = e0[i], a1 = e1[i], a2 = e2[i], a3 = e3[i];
    #pragma unroll
    for (int jj = 0; jj < 8; ++jj) {
      float4 wv = w_lds[((jh * 8 + jj) * 16 + i) * CC + c];
      acc0[jj] += wv.x * a0.x + wv.y * a0.y + wv.z * a0.z + wv.w * a0.w;
      acc1[jj] += wv.x * a1.x + wv.y * a1.y + wv.z * a1.z + wv.w * a1.w;
      acc2[jj] += wv.x * a2.x + wv.y * a2.y + wv.z * a2.z + wv.w * a2.w;
      acc3[jj] += wv.x * a3.x + wv.y * a3.y + wv.z * a3.z + wv.w * a3.w;
    }
  }

  float s0 = 0.f, s1 = 0.f, s2 = 0.f, s3 = 0.f;
  #pragma unroll
  for (int jj = 0; jj < 8; ++jj) {
    float w2v = w2_s[c * HH + jh * 8 + jj];
    s0 += w2v * fmaxf(acc0[jj], 0.f);
    s1 += w2v * fmaxf(acc1[jj], 0.f);
    s2 += w2v * fmaxf(acc2[jj], 0.f);
    s3 += w2v * fmaxf(acc3[jj], 0.f);
  }
  // combine j-halves (partner lane = lane^1, always active together)
  s0 += __shfl_xor(s0, 1, 64);
  s1 += __shfl_xor(s1, 1, 64);
  s2 += __shfl_xor(s2, 1, 64);
  s3 += __shfl_xor(s3, 1, 64);

  if (jh == 0) {
    const float b2c = b2_s[c];
    *(float4*)&z_g[base] = make_float4(expf(s0 + b2c), expf(s1 + b2c),
                                       expf(s2 + b2c), expf(s3 + b2c));
  }
}

// kCD: per-user 256-thread block. 4 waves iterate categories {w, w+4, w+8} with
// float4-lane gvec; gvec in LDS; fused top-level attention + output.
// NOTE: zv is per-lane distinct -> zs needs the FULL 64-lane butterfly (r14 bug).
__global__ __launch_bounds__(256) void din_kcd(
    const int* __restrict__ user_inputs,
    const int* __restrict__ item_inputs,
    const float* __restrict__ user_emb,
    const float* __restrict__ item_emb,
    const float* __restrict__ Wt1,
    const float* __restrict__ bt1,
    const float* __restrict__ Wt2,
    const float* __restrict__ bt2,
    const int* __restrict__ srow_g,
    const float* __restrict__ z_g,
    const int* __restrict__ cstart_g,
    float* __restrict__ out)
{
  const int b = blockIdx.x;
  const int t = threadIdx.x;
  const int wave = t >> 6, lane = t & 63;
  const int g = lane >> 4;         // item subgroup 0..3
  const int h = lane & 15;         // d-quad (d = 4h..4h+3)

  __shared__ float u_s[DD];
  __shared__ float gvec_s[CC][DD];
  __shared__ float h2_s[CC][HH];
  __shared__ float w2t_s[CC];
  __shared__ int   cnt_s[CC];

  if (t < DD) u_s[t] = user_emb[(size_t)user_inputs[b] * DD + t];

  for (int c = wave; c < CC; c += NW) {
    const int i0 = cstart_g[b * 20 + c];
    const int n  = cstart_g[b * 20 + 10 + c];
    if (lane == 0) cnt_s[c] = n;
    const int sb = b * PADL + i0;

    float4 acc = make_float4(0.f, 0.f, 0.f, 0.f);
    float  zs  = 0.f;

    for (int cb = 0; cb < n; cb += 64) {
      const int nn = min(64, n - cb);
      const bool ok = (cb + lane) < n;
      int   rv = ok ? srow_g[sb + cb + lane] : 0;   // coalesced
      float zv = ok ? z_g[sb + cb + lane]    : 0.f;
      zs += zv;

      const int kmax = (nn + 3) >> 2;
      #pragma unroll 4
      for (int k = 0; k < kmax; ++k) {
        const int j = 4 * k + g;
        const int   rr = __shfl(rv, j, 64);
        const float zz = __shfl(zv, j, 64);         // 0 for pad items
        const float4 ev = *(const float4*)&item_emb[(size_t)rr * DD + 4 * h];
        acc.x += zz * ev.x; acc.y += zz * ev.y;
        acc.z += zz * ev.z; acc.w += zz * ev.w;
      }
    }

    // acc: combine the 4 item-subgroups only (bits 4,5)
    acc.x += __shfl_xor(acc.x, 16, 64); acc.y += __shfl_xor(acc.y, 16, 64);
    acc.z += __shfl_xor(acc.z, 16, 64); acc.w += __shfl_xor(acc.w, 16, 64);
    acc.x += __shfl_xor(acc.x, 32, 64); acc.y += __shfl_xor(acc.y, 32, 64);
    acc.z += __shfl_xor(acc.z, 32, 64); acc.w += __shfl_xor(acc.w, 32, 64);
    // zs: per-lane partials -> FULL 64-lane butterfly
    #pragma unroll
    for (int off = 32; off > 0; off >>= 1) zs += __shfl_xor(zs, off, 64);

    if (g == 0) {
      const float inv = 1.f / fmaxf(zs, 1e-30f);
      gvec_s[c][4 * h + 0] = acc.x * inv;
      gvec_s[c][4 * h + 1] = acc.y * inv;
      gvec_s[c][4 * h + 2] = acc.z * inv;
      gvec_s[c][4 * h + 3] = acc.w * inv;   // empty cat -> 0
    }
  }
  __syncthreads();

  // ---- top-level attention ----
  if (t < CC * HH) {
    int cc = t / HH, j = t % HH;
    const float* wp = &Wt1[(size_t)j * (2 * DD)];
    float a = bt1[j];
    #pragma unroll 8
    for (int d = 0; d < DD; ++d) a += wp[d] * u_s[d];
    #pragma unroll 8
    for (int d = 0; d < DD; ++d) a += wp[DD + d] * gvec_s[cc][d];
    h2_s[cc][j] = fmaxf(a, 0.f);
  }
  __syncthreads();

  if (t == 0) {
    float s2[CC];
    float m = -INFINITY;
    #pragma unroll
    for (int cc = 0; cc < CC; ++cc) {
      float a = bt2[0];
      #pragma unroll
      for (int j = 0; j < HH; ++j) a += Wt2[j] * h2_s[cc][j];
      s2[cc] = a;
      if (cnt_s[cc] > 0) m = fmaxf(m, a);
    }
    if (m == -INFINITY) m = 0.f;
    float sum = 0.f;
    float z2[CC];
    #pragma unroll
    for (int cc = 0; cc < CC; ++cc) {
      z2[cc] = (cnt_s[cc] > 0) ? expf(s2[cc] - m) : 0.f;
      sum += z2[cc];
    }
    float inv = 1.f / fmaxf(sum, 1e-30f);
    #pragma unroll
    for (int cc = 0; cc < CC; ++cc) w2t_s[cc] = z2[cc] * inv;
  }
  __syncthreads();

  if (t < DD) {
    float hy = 0.f;
    #pragma unroll
    for (int cc = 0; cc < CC; ++cc) hy += w2t_s[cc] * gvec_s[cc][t];
    float ti = item_emb[(size_t)item_inputs[b] * DD + t];
    float prod = hy * ti;
    #pragma unroll
    for (int off = 32; off > 0; off >>= 1)
      prod += __shfl_down(prod, off, 64);
    if (t == 0) out[b] = prod;
  }
}

extern "C" void kernel_launch(void* const* d_in, const int* in_sizes, int n_in,
                              void* d_out, int out_size, void* d_ws, size_t ws_size,
                              hipStream_t stream) {
  const int*   user_inputs   = (const int*)d_in[0];
  const int*   record_inputs = (const int*)d_in[1];
  const int*   item_inputs   = (const int*)d_in[2];
  const int*   item_cat      = (const int*)d_in[3];
  const float* user_emb      = (const float*)d_in[4];
  const float* item_emb      = (const float*)d_in[5];
  const float* W1            = (const float*)d_in[6];
  const float* b1            = (const float*)d_in[7];
  const float* W2            = (const float*)d_in[8];
  const float* b2            = (const float*)d_in[9];
  const float* Wt1           = (const float*)d_in[10];
  const float* bt1           = (const float*)d_in[11];
  const float* Wt2           = (const float*)d_in[12];
  const float* bt2           = (const float*)d_in[13];
  float* out = (float*)d_out;

  char* ws = (char*)d_ws;
  int*   srow_g   = (int*)(ws);                 // B*PADL ints
  float* z_g      = (float*)(ws + 2097152);     // B*PADL floats
  int*   cstart_g = (int*)(ws + 4194304);       // B*20 ints
  float* pre_g    = (float*)(ws + 4358144);     // B*C*H floats

  din_ka<<<NB, 256, 0, stream>>>(user_inputs, record_inputs, item_cat,
                                 user_emb, W1, b1, srow_g, cstart_g, pre_g);
  din_kb<<<NB / 2, 256, 0, stream>>>(item_emb, W1, W2, b2,
                                     srow_g, cstart_g, pre_g, z_g);
  din_kcd<<<NB, 256, 0, stream>>>(user_inputs, item_inputs, user_emb, item_emb,
                                  Wt1, bt1, Wt2, bt2,
                                  srow_g, z_g, cstart_g, out);
}

// Round 16
// 70.376 us; speedup vs baseline: 1.1870x; 1.1203x over previous
//
#include <hip/hip_runtime.h>
#include <math.h>

#define NB 2048
#define LL 200
#define PADL 256   // padded per-user slot stride
#define DD 64
#define CC 9
#define HH 16
#define NW 4

// ---- d_ws layout (bytes) ----
// srow_g : int  [B*PADL]  @ 0          (2,097,152)
// z_g    : float[B*PADL]  @ 2,097,152  (2,097,152)
// cstart : int  [B*20]    @ 4,194,304  (163,840)  [0..9]=padded starts(+total@9), [10..18]=counts

// K1: per-user block. Ballot sort (4-aligned padded groups) + W1-ehalf -> LDS +
// score with (group, j-quarter) split: 4 threads x 4 items x 4 hidden units,
// 16 ds_read_b128/item, j-quarters combined via shfl_xor(1,2). z = exp(s) (M=0).
__global__ __launch_bounds__(256) void din_k1(
    const int* __restrict__ user_inputs,
    const int* __restrict__ record_inputs,
    const int* __restrict__ item_cat,
    const float* __restrict__ user_emb,
    const float* __restrict__ item_emb,
    const float* __restrict__ W1,
    const float* __restrict__ b1,
    const float* __restrict__ W2,
    const float* __restrict__ b2,
    int* __restrict__ srow_g,
    float* __restrict__ z_g,
    int* __restrict__ cstart_g)
{
  const int b = blockIdx.x;
  const int t = threadIdx.x;
  const int wave = t >> 6, lane = t & 63;

  __shared__ float4 w_lds[HH * 16 * CC];   // 36.9 KB, [ (j*16+i) ][ c ]
  __shared__ float  w2_s[CC * HH];
  __shared__ float  b2_s[CC];
  __shared__ float  u_s[DD];
  __shared__ float  pre_s[CC][HH];
  __shared__ int    wcnt[NW][CC];
  __shared__ int    cstart[CC + 1];
  __shared__ int    ccnt[CC];
  __shared__ int    srow_sh[PADL];

  // ---- stage W (no dependency on sort) ----
  #pragma unroll
  for (int k = t; k < HH * 16 * CC; k += 256) {
    int c = k >> 8;
    int ji = k & 255;
    int j = ji >> 4, i = ji & 15;
    w_lds[ji * CC + c] = ((const float4*)W1)[(size_t)(c * HH + j) * 32 + 16 + i];
  }
  if (t < CC * HH) w2_s[t] = W2[t];
  if (t < CC) b2_s[t] = b2[t];

  // ---- sort inputs ----
  int r = -1, c0 = -1;
  if (t < LL) {
    r = record_inputs[b * LL + t];
    if (r >= 0) c0 = item_cat[r];
  }
  if (t < DD) u_s[t] = user_emb[(size_t)user_inputs[b] * DD + t];
  srow_sh[t] = 0;
  srow_g[b * PADL + t] = 0;   // pad slots -> row 0

  int myrank = 0;
  #pragma unroll
  for (int c = 0; c < CC; ++c) {
    unsigned long long m = __ballot(c0 == c);
    if (lane == 0) wcnt[wave][c] = __popcll(m);
    if (c0 == c) myrank = __popcll(m & ((1ULL << lane) - 1ULL));
  }
  __syncthreads();

  if (t == 0) {
    int acc = 0;
    #pragma unroll
    for (int c = 0; c < CC; ++c) {
      cstart[c] = acc;
      int cn = wcnt[0][c] + wcnt[1][c] + wcnt[2][c] + wcnt[3][c];
      ccnt[c] = cn;
      acc = (acc + cn + 3) & ~3;   // 4-aligned next group
    }
    cstart[CC] = acc;
  }
  if (t < CC * HH) {   // pre = b1 + W1u . u  (stays in LDS)
    int c = t / HH, j = t % HH;
    const float* wp = &W1[(size_t)(c * HH + j) * (2 * DD)];
    float acc = b1[c * HH + j];
    #pragma unroll 8
    for (int d = 0; d < DD; ++d) acc += wp[d] * u_s[d];
    pre_s[c][j] = acc;
  }
  __syncthreads();

  if (c0 >= 0) {
    int off = cstart[c0];
    for (int w = 0; w < wave; ++w) off += wcnt[w][c0];
    int pos = off + myrank;
    srow_sh[pos] = r;
    srow_g[b * PADL + pos] = r;
  }
  if (t < CC + 1) cstart_g[b * 20 + t] = cstart[t];
  else if (t < 2 * CC + 1) cstart_g[b * 20 + 10 + (t - CC - 1)] = ccnt[t - CC - 1];
  __syncthreads();

  // ---- score: thread = (grp, jq); 4 items, 4 hidden units each ----
  const int ntot = cstart[CC];          // padded total (<= 228)
  const int grp  = t >> 2;              // item group
  const int jq   = t & 3;               // j-quarter
  const int q4   = grp * 4;
  if (q4 < ntot) {
    int c = 0;
    #pragma unroll
    for (int q = 0; q < CC - 1; ++q) c += (q4 >= cstart[q + 1]) ? 1 : 0;

    const int r0 = srow_sh[q4 + 0], r1 = srow_sh[q4 + 1];
    const int r2 = srow_sh[q4 + 2], r3 = srow_sh[q4 + 3];
    const float4* e0 = (const float4*)&item_emb[(size_t)r0 * DD];
    const float4* e1 = (const float4*)&item_emb[(size_t)r1 * DD];
    const float4* e2 = (const float4*)&item_emb[(size_t)r2 * DD];
    const float4* e3 = (const float4*)&item_emb[(size_t)r3 * DD];

    float acc0[4], acc1[4], acc2[4], acc3[4];
    #pragma unroll
    for (int jj = 0; jj < 4; ++jj) {
      float pv = pre_s[c][jq * 4 + jj];
      acc0[jj] = pv; acc1[jj] = pv; acc2[jj] = pv; acc3[jj] = pv;
    }

    #pragma unroll
    for (int i = 0; i < 16; ++i) {
      float4 a0 = e0[i], a1 = e1[i], a2 = e2[i], a3 = e3[i];
      #pragma unroll
      for (int jj = 0; jj < 4; ++jj) {
        float4 wv = w_lds[((jq * 4 + jj) * 16 + i) * CC + c];
        acc0[jj] += wv.x * a0.x + wv.y * a0.y + wv.z * a0.z + wv.w * a0.w;
        acc1[jj] += wv.x * a1.x + wv.y * a1.y + wv.z * a1.z + wv.w * a1.w;
        acc2[jj] += wv.x * a2.x + wv.y * a2.y + wv.z * a2.z + wv.w * a2.w;
        acc3[jj] += wv.x * a3.x + wv.y * a3.y + wv.z * a3.z + wv.w * a3.w;
      }
    }

    float s0 = 0.f, s1 = 0.f, s2 = 0.f, s3 = 0.f;
    #pragma unroll
    for (int jj = 0; jj < 4; ++jj) {
      float w2v = w2_s[c * HH + jq * 4 + jj];
      s0 += w2v * fmaxf(acc0[jj], 0.f);
      s1 += w2v * fmaxf(acc1[jj], 0.f);
      s2 += w2v * fmaxf(acc2[jj], 0.f);
      s3 += w2v * fmaxf(acc3[jj], 0.f);
    }
    // combine j-quarters (lanes differ in bits 0,1; all 4 lanes of a grp active)
    s0 += __shfl_xor(s0, 1, 64); s0 += __shfl_xor(s0, 2, 64);
    s1 += __shfl_xor(s1, 1, 64); s1 += __shfl_xor(s1, 2, 64);
    s2 += __shfl_xor(s2, 1, 64); s2 += __shfl_xor(s2, 2, 64);
    s3 += __shfl_xor(s3, 1, 64); s3 += __shfl_xor(s3, 2, 64);

    if (jq == 0) {
      const float b2c = b2_s[c];
      *(float4*)&z_g[b * PADL + q4] = make_float4(expf(s0 + b2c), expf(s1 + b2c),
                                                  expf(s2 + b2c), expf(s3 + b2c));
    }
  }
}

// K2: per-user 256-thread block (verbatim round 15). 4 waves x cats {w,w+4,w+8},
// float4-lane gvec, full 64-lane butterfly for zs, fused top attention + output.
__global__ __launch_bounds__(256) void din_kcd(
    const int* __restrict__ user_inputs,
    const int* __restrict__ item_inputs,
    const float* __restrict__ user_emb,
    const float* __restrict__ item_emb,
    const float* __restrict__ Wt1,
    const float* __restrict__ bt1,
    const float* __restrict__ Wt2,
    const float* __restrict__ bt2,
    const int* __restrict__ srow_g,
    const float* __restrict__ z_g,
    const int* __restrict__ cstart_g,
    float* __restrict__ out)
{
  const int b = blockIdx.x;
  const int t = threadIdx.x;
  const int wave = t >> 6, lane = t & 63;
  const int g = lane >> 4;         // item subgroup 0..3
  const int h = lane & 15;         // d-quad (d = 4h..4h+3)

  __shared__ float u_s[DD];
  __shared__ float gvec_s[CC][DD];
  __shared__ float h2_s[CC][HH];
  __shared__ float w2t_s[CC];
  __shared__ int   cnt_s[CC];

  if (t < DD) u_s[t] = user_emb[(size_t)user_inputs[b] * DD + t];

  for (int c = wave; c < CC; c += NW) {
    const int i0 = cstart_g[b * 20 + c];
    const int n  = cstart_g[b * 20 + 10 + c];
    if (lane == 0) cnt_s[c] = n;
    const int sb = b * PADL + i0;

    float4 acc = make_float4(0.f, 0.f, 0.f, 0.f);
    float  zs  = 0.f;

    for (int cb = 0; cb < n; cb += 64) {
      const int nn = min(64, n - cb);
      const bool ok = (cb + lane) < n;
      int   rv = ok ? srow_g[sb + cb + lane] : 0;   // coalesced
      float zv = ok ? z_g[sb + cb + lane]    : 0.f;
      zs += zv;

      const int kmax = (nn + 3) >> 2;
      #pragma unroll 4
      for (int k = 0; k < kmax; ++k) {
        const int j = 4 * k + g;
        const int   rr = __shfl(rv, j, 64);
        const float zz = __shfl(zv, j, 64);         // 0 for pad items
        const float4 ev = *(const float4*)&item_emb[(size_t)rr * DD + 4 * h];
        acc.x += zz * ev.x; acc.y += zz * ev.y;
        acc.z += zz * ev.z; acc.w += zz * ev.w;
      }
    }

    // acc: combine the 4 item-subgroups only (bits 4,5)
    acc.x += __shfl_xor(acc.x, 16, 64); acc.y += __shfl_xor(acc.y, 16, 64);
    acc.z += __shfl_xor(acc.z, 16, 64); acc.w += __shfl_xor(acc.w, 16, 64);
    acc.x += __shfl_xor(acc.x, 32, 64); acc.y += __shfl_xor(acc.y, 32, 64);
    acc.z += __shfl_xor(acc.z, 32, 64); acc.w += __shfl_xor(acc.w, 32, 64);
    // zs: per-lane partials -> FULL 64-lane butterfly
    #pragma unroll
    for (int off = 32; off > 0; off >>= 1) zs += __shfl_xor(zs, off, 64);

    if (g == 0) {
      const float inv = 1.f / fmaxf(zs, 1e-30f);
      gvec_s[c][4 * h + 0] = acc.x * inv;
      gvec_s[c][4 * h + 1] = acc.y * inv;
      gvec_s[c][4 * h + 2] = acc.z * inv;
      gvec_s[c][4 * h + 3] = acc.w * inv;   // empty cat -> 0
    }
  }
  __syncthreads();

  // ---- top-level attention ----
  if (t < CC * HH) {
    int cc = t / HH, j = t % HH;
    const float* wp = &Wt1[(size_t)j * (2 * DD)];
    float a = bt1[j];
    #pragma unroll 8
    for (int d = 0; d < DD; ++d) a += wp[d] * u_s[d];
    #pragma unroll 8
    for (int d = 0; d < DD; ++d) a += wp[DD + d] * gvec_s[cc][d];
    h2_s[cc][j] = fmaxf(a, 0.f);
  }
  __syncthreads();

  if (t == 0) {
    float s2[CC];
    float m = -INFINITY;
    #pragma unroll
    for (int cc = 0; cc < CC; ++cc) {
      float a = bt2[0];
      #pragma unroll
      for (int j = 0; j < HH; ++j) a += Wt2[j] * h2_s[cc][j];
      s2[cc] = a;
      if (cnt_s[cc] > 0) m = fmaxf(m, a);
    }
    if (m == -INFINITY) m = 0.f;
    float sum = 0.f;
    float z2[CC];
    #pragma unroll
    for (int cc = 0; cc < CC; ++cc) {
      z2[cc] = (cnt_s[cc] > 0) ? expf(s2[cc] - m) : 0.f;
      sum += z2[cc];
    }
    float inv = 1.f / fmaxf(sum, 1e-30f);
    #pragma unroll
    for (int cc = 0; cc < CC; ++cc) w2t_s[cc] = z2[cc] * inv;
  }
  __syncthreads();

  if (t < DD) {
    float hy = 0.f;
    #pragma unroll
    for (int cc = 0; cc < CC; ++cc) hy += w2t_s[cc] * gvec_s[cc][t];
    float ti = item_emb[(size_t)item_inputs[b] * DD + t];
    float prod = hy * ti;
    #pragma unroll
    for (int off = 32; off > 0; off >>= 1)
      prod += __shfl_down(prod, off, 64);
    if (t == 0) out[b] = prod;
  }
}

extern "C" void kernel_launch(void* const* d_in, const int* in_sizes, int n_in,
                              void* d_out, int out_size, void* d_ws, size_t ws_size,
                              hipStream_t stream) {
  const int*   user_inputs   = (const int*)d_in[0];
  const int*   record_inputs = (const int*)d_in[1];
  const int*   item_inputs   = (const int*)d_in[2];
  const int*   item_cat      = (const int*)d_in[3];
  const float* user_emb      = (const float*)d_in[4];
  const float* item_emb      = (const float*)d_in[5];
  const float* W1            = (const float*)d_in[6];
  const float* b1            = (const float*)d_in[7];
  const float* W2            = (const float*)d_in[8];
  const float* b2            = (const float*)d_in[9];
  const float* Wt1           = (const float*)d_in[10];
  const float* bt1           = (const float*)d_in[11];
  const float* Wt2           = (const float*)d_in[12];
  const float* bt2           = (const float*)d_in[13];
  float* out = (float*)d_out;

  char* ws = (char*)d_ws;
  int*   srow_g   = (int*)(ws);                 // B*PADL ints
  float* z_g      = (float*)(ws + 2097152);     // B*PADL floats
  int*   cstart_g = (int*)(ws + 4194304);       // B*20 ints

  din_k1<<<NB, 256, 0, stream>>>(user_inputs, record_inputs, item_cat,
                                 user_emb, item_emb, W1, b1, W2, b2,
                                 srow_g, z_g, cstart_g);
  din_kcd<<<NB, 256, 0, stream>>>(user_inputs, item_inputs, user_emb, item_emb,
                                  Wt1, bt1, Wt2, bt2,
                                  srow_g, z_g, cstart_g, out);
}

// Round 17
// 70.192 us; speedup vs baseline: 1.1901x; 1.0026x over previous
//
#include <hip/hip_runtime.h>
#include <math.h>

#define NB 2048
#define LL 200
#define PADL 256
#define DD 64
#define CC 9
#define HH 16
#define NW 4

// Single fused per-user kernel:
//   A: W1-ehalf -> LDS (XOR-swizzled), ballot sort, pre = b1 + W1u.u
//   B: score MLP (grp,jq split; 16 swizzled ds_read_b128/item), z = exp(s) -> LDS
//   C: gvec per category (wave = cat; float4 lanes; srow/z from LDS broadcast)
//   D: top attention + output
__global__ __launch_bounds__(256) void din_fused(
    const int* __restrict__ user_inputs,
    const int* __restrict__ record_inputs,
    const int* __restrict__ item_inputs,
    const int* __restrict__ item_cat,
    const float* __restrict__ user_emb,
    const float* __restrict__ item_emb,
    const float* __restrict__ W1,
    const float* __restrict__ b1,
    const float* __restrict__ W2,
    const float* __restrict__ b2,
    const float* __restrict__ Wt1,
    const float* __restrict__ bt1,
    const float* __restrict__ Wt2,
    const float* __restrict__ bt2,
    float* __restrict__ out)
{
  const int b = blockIdx.x;
  const int t = threadIdx.x;
  const int wave = t >> 6, lane = t & 63;

  __shared__ float4 w_lds[HH * 16 * CC];   // 36.9 KB, phys = (ji*CC+c) ^ (jq<<1)
  __shared__ float  w2_s[CC * HH];
  __shared__ float  b2_s[CC];
  __shared__ float  u_s[DD];
  __shared__ float  pre_s[CC][HH];
  __shared__ int    wcnt[NW][CC];
  __shared__ int    cstart[CC + 1];
  __shared__ int    ccnt[CC];
  __shared__ int    srow_sh[PADL];
  __shared__ float  z_s[PADL];
  __shared__ float  gvec_s[CC][DD];
  __shared__ float  h2_s[CC][HH];
  __shared__ float  w2t_s[CC];

  // ---- Phase A: stage W (swizzled) + inputs + ballot count ----
  #pragma unroll
  for (int k = t; k < HH * 16 * CC; k += 256) {
    int c = k >> 8;
    int ji = k & 255;                      // j*16 + i
    int j = ji >> 4, i = ji & 15;
    int phys = (ji * CC + c) ^ ((ji >> 6) << 1);   // jq = ji>>6 spreads banks
    w_lds[phys] = ((const float4*)W1)[(size_t)(c * HH + j) * 32 + 16 + i];
  }
  if (t < CC * HH) w2_s[t] = W2[t];
  if (t < CC) b2_s[t] = b2[t];

  int r = -1, c0 = -1;
  if (t < LL) {
    r = record_inputs[b * LL + t];
    if (r >= 0) c0 = item_cat[r];
  }
  if (t < DD) u_s[t] = user_emb[(size_t)user_inputs[b] * DD + t];
  srow_sh[t] = 0;                          // pad slots -> row 0

  int myrank = 0;
  #pragma unroll
  for (int c = 0; c < CC; ++c) {
    unsigned long long m = __ballot(c0 == c);
    if (lane == 0) wcnt[wave][c] = __popcll(m);
    if (c0 == c) myrank = __popcll(m & ((1ULL << lane) - 1ULL));
  }
  __syncthreads();

  if (t == 0) {
    int acc = 0;
    #pragma unroll
    for (int c = 0; c < CC; ++c) {
      cstart[c] = acc;
      int cn = wcnt[0][c] + wcnt[1][c] + wcnt[2][c] + wcnt[3][c];
      ccnt[c] = cn;
      acc = (acc + cn + 3) & ~3;           // 4-aligned groups
    }
    cstart[CC] = acc;
  }
  if (t < CC * HH) {                       // pre = b1 + W1u . u
    int c = t / HH, j = t % HH;
    const float* wp = &W1[(size_t)(c * HH + j) * (2 * DD)];
    float acc = b1[c * HH + j];
    #pragma unroll 8
    for (int d = 0; d < DD; ++d) acc += wp[d] * u_s[d];
    pre_s[c][j] = acc;
  }
  __syncthreads();

  if (c0 >= 0) {                           // stable scatter
    int off = cstart[c0];
    for (int w = 0; w < wave; ++w) off += wcnt[w][c0];
    srow_sh[off + myrank] = r;
  }
  __syncthreads();

  // ---- Phase B: score; thread = (grp, jq): 4 items x 4 hidden units ----
  const int ntot = cstart[CC];             // padded total (<= 228)
  {
    const int grp = t >> 2, jq = t & 3;
    const int q4 = grp * 4;
    if (q4 < ntot) {
      int c = 0;
      #pragma unroll
      for (int q = 0; q < CC - 1; ++q) c += (q4 >= cstart[q + 1]) ? 1 : 0;

      const int r0 = srow_sh[q4 + 0], r1 = srow_sh[q4 + 1];
      const int r2 = srow_sh[q4 + 2], r3 = srow_sh[q4 + 3];
      const float4* e0 = (const float4*)&item_emb[(size_t)r0 * DD];
      const float4* e1 = (const float4*)&item_emb[(size_t)r1 * DD];
      const float4* e2 = (const float4*)&item_emb[(size_t)r2 * DD];
      const float4* e3 = (const float4*)&item_emb[(size_t)r3 * DD];

      float acc0[4], acc1[4], acc2[4], acc3[4];
      #pragma unroll
      for (int jj = 0; jj < 4; ++jj) {
        float pv = pre_s[c][jq * 4 + jj];
        acc0[jj] = pv; acc1[jj] = pv; acc2[jj] = pv; acc3[jj] = pv;
      }

      #pragma unroll
      for (int i = 0; i < 16; ++i) {
        float4 a0 = e0[i], a1 = e1[i], a2 = e2[i], a3 = e3[i];
        #pragma unroll
        for (int jj = 0; jj < 4; ++jj) {
          int ji = (jq * 4 + jj) * 16 + i;
          float4 wv = w_lds[(ji * CC + c) ^ (jq << 1)];
          acc0[jj] += wv.x * a0.x + wv.y * a0.y + wv.z * a0.z + wv.w * a0.w;
          acc1[jj] += wv.x * a1.x + wv.y * a1.y + wv.z * a1.z + wv.w * a1.w;
          acc2[jj] += wv.x * a2.x + wv.y * a2.y + wv.z * a2.z + wv.w * a2.w;
          acc3[jj] += wv.x * a3.x + wv.y * a3.y + wv.z * a3.z + wv.w * a3.w;
        }
      }

      float s0 = 0.f, s1 = 0.f, s2 = 0.f, s3 = 0.f;
      #pragma unroll
      for (int jj = 0; jj < 4; ++jj) {
        float w2v = w2_s[c * HH + jq * 4 + jj];
        s0 += w2v * fmaxf(acc0[jj], 0.f);
        s1 += w2v * fmaxf(acc1[jj], 0.f);
        s2 += w2v * fmaxf(acc2[jj], 0.f);
        s3 += w2v * fmaxf(acc3[jj], 0.f);
      }
      s0 += __shfl_xor(s0, 1, 64); s0 += __shfl_xor(s0, 2, 64);
      s1 += __shfl_xor(s1, 1, 64); s1 += __shfl_xor(s1, 2, 64);
      s2 += __shfl_xor(s2, 1, 64); s2 += __shfl_xor(s2, 2, 64);
      s3 += __shfl_xor(s3, 1, 64); s3 += __shfl_xor(s3, 2, 64);

      if (jq == 0) {
        const float b2c = b2_s[c];
        *(float4*)&z_s[q4] = make_float4(expf(s0 + b2c), expf(s1 + b2c),
                                         expf(s2 + b2c), expf(s3 + b2c));
      }
    }
  }
  __syncthreads();

  // ---- Phase C: gvec. wave = category loop; lane (g,h); srow/z from LDS ----
  {
    const int g = lane >> 4, h = lane & 15;
    for (int c = wave; c < CC; c += NW) {
      const int i0 = cstart[c], n = ccnt[c];
      float4 acc = make_float4(0.f, 0.f, 0.f, 0.f);
      float  zs  = 0.f;
      const int kmax = (n + 3) >> 2;
      #pragma unroll 4
      for (int k = 0; k < kmax; ++k) {
        const int io = 4 * k + g;
        const int rr = srow_sh[i0 + io];              // broadcast (4 addrs)
        const float zz = (io < n) ? z_s[i0 + io] : 0.f;
        const float4 ev = *(const float4*)&item_emb[(size_t)rr * DD + 4 * h];
        acc.x += zz * ev.x; acc.y += zz * ev.y;
        acc.z += zz * ev.z; acc.w += zz * ev.w;
        zs += zz;                                     // uniform within h-group
      }
      // combine 4 item-subgroups (bits 4,5); zs is h-uniform so same butterfly
      acc.x += __shfl_xor(acc.x, 16, 64); acc.y += __shfl_xor(acc.y, 16, 64);
      acc.z += __shfl_xor(acc.z, 16, 64); acc.w += __shfl_xor(acc.w, 16, 64);
      acc.x += __shfl_xor(acc.x, 32, 64); acc.y += __shfl_xor(acc.y, 32, 64);
      acc.z += __shfl_xor(acc.z, 32, 64); acc.w += __shfl_xor(acc.w, 32, 64);
      zs += __shfl_xor(zs, 16, 64);
      zs += __shfl_xor(zs, 32, 64);

      if (g == 0) {
        const float inv = 1.f / fmaxf(zs, 1e-30f);
        gvec_s[c][4 * h + 0] = acc.x * inv;
        gvec_s[c][4 * h + 1] = acc.y * inv;
        gvec_s[c][4 * h + 2] = acc.z * inv;
        gvec_s[c][4 * h + 3] = acc.w * inv;           // empty cat -> 0
      }
    }
  }
  __syncthreads();

  // ---- Phase D: top-level attention + output ----
  if (t < CC * HH) {
    int cc = t / HH, j = t % HH;
    const float* wp = &Wt1[(size_t)j * (2 * DD)];
    float a = bt1[j];
    #pragma unroll 8
    for (int d = 0; d < DD; ++d) a += wp[d] * u_s[d];
    #pragma unroll 8
    for (int d = 0; d < DD; ++d) a += wp[DD + d] * gvec_s[cc][d];
    h2_s[cc][j] = fmaxf(a, 0.f);
  }
  __syncthreads();

  if (t == 0) {
    float s2[CC];
    float m = -INFINITY;
    #pragma unroll
    for (int cc = 0; cc < CC; ++cc) {
      float a = bt2[0];
      #pragma unroll
      for (int j = 0; j < HH; ++j) a += Wt2[j] * h2_s[cc][j];
      s2[cc] = a;
      if (ccnt[cc] > 0) m = fmaxf(m, a);
    }
    if (m == -INFINITY) m = 0.f;
    float sum = 0.f;
    float z2[CC];
    #pragma unroll
    for (int cc = 0; cc < CC; ++cc) {
      z2[cc] = (ccnt[cc] > 0) ? expf(s2[cc] - m) : 0.f;
      sum += z2[cc];
    }
    float inv = 1.f / fmaxf(sum, 1e-30f);
    #pragma unroll
    for (int cc = 0; cc < CC; ++cc) w2t_s[cc] = z2[cc] * inv;
  }
  __syncthreads();

  if (t < DD) {
    float hy = 0.f;
    #pragma unroll
    for (int cc = 0; cc < CC; ++cc) hy += w2t_s[cc] * gvec_s[cc][t];
    float ti = item_emb[(size_t)item_inputs[b] * DD + t];
    float prod = hy * ti;
    #pragma unroll
    for (int off = 32; off > 0; off >>= 1)
      prod += __shfl_down(prod, off, 64);
    if (t == 0) out[b] = prod;
  }
}

extern "C" void kernel_launch(void* const* d_in, const int* in_sizes, int n_in,
                              void* d_out, int out_size, void* d_ws, size_t ws_size,
                              hipStream_t stream) {
  const int*   user_inputs   = (const int*)d_in[0];
  const int*   record_inputs = (const int*)d_in[1];
  const int*   item_inputs   = (const int*)d_in[2];
  const int*   item_cat      = (const int*)d_in[3];
  const float* user_emb      = (const float*)d_in[4];
  const float* item_emb      = (const float*)d_in[5];
  const float* W1            = (const float*)d_in[6];
  const float* b1            = (const float*)d_in[7];
  const float* W2            = (const float*)d_in[8];
  const float* b2            = (const float*)d_in[9];
  const float* Wt1           = (const float*)d_in[10];
  const float* bt1           = (const float*)d_in[11];
  const float* Wt2           = (const float*)d_in[12];
  const float* bt2           = (const float*)d_in[13];
  float* out = (float*)d_out;

  din_fused<<<NB, 256, 0, stream>>>(user_inputs, record_inputs, item_inputs,
                                    item_cat, user_emb, item_emb,
                                    W1, b1, W2, b2, Wt1, bt1, Wt2, bt2, out);
}

// Round 18
// 65.408 us; speedup vs baseline: 1.2771x; 1.0731x over previous
//
#include <hip/hip_runtime.h>
#include <math.h>

#define NB 2048
#define LL 200
#define PADL 256
#define DD 64
#define CC 9
#define HH 16
#define NW 4
#define UPB 2   // users per block (512 threads)

// Fused per-2-user kernel. W1-ehalf staged ONCE per block (shared by both users):
//   A: W -> LDS (XOR-swizzled), per-user ballot sort, pre = b1 + W1u.u
//   B: score MLP (grp,jq split), z = exp(s) -> LDS
//   C: gvec per category (per-user wave = cat; float4 lanes)
//   D: top attention + output
__global__ __launch_bounds__(512) void din_fused(
    const int* __restrict__ user_inputs,
    const int* __restrict__ record_inputs,
    const int* __restrict__ item_inputs,
    const int* __restrict__ item_cat,
    const float* __restrict__ user_emb,
    const float* __restrict__ item_emb,
    const float* __restrict__ W1,
    const float* __restrict__ b1,
    const float* __restrict__ W2,
    const float* __restrict__ b2,
    const float* __restrict__ Wt1,
    const float* __restrict__ bt1,
    const float* __restrict__ Wt2,
    const float* __restrict__ bt2,
    float* __restrict__ out)
{
  const int t  = threadIdx.x;           // 0..511
  const int uu = t >> 8;                // local user 0/1
  const int tu = t & 255;               // per-user thread index
  const int b  = blockIdx.x * UPB + uu;
  const int wave = tu >> 6, lane = t & 63;

  __shared__ float4 w_lds[HH * 16 * CC];     // 36.9 KB, shared by both users
  __shared__ float  w2_s[CC * HH];
  __shared__ float  b2_s[CC];
  __shared__ float  u_s[UPB][DD];
  __shared__ float  pre_s[UPB][CC][HH];
  __shared__ int    wcnt[UPB][NW][CC];
  __shared__ int    cstart[UPB][CC + 1];
  __shared__ int    ccnt[UPB][CC];
  __shared__ int    srow_sh[UPB][PADL];
  __shared__ float  z_s[UPB][PADL];
  __shared__ float  gvec_s[UPB][CC][DD];
  __shared__ float  h2_s[UPB][CC][HH];
  __shared__ float  w2t_s[UPB][CC];

  // ---- Phase A: stage W (swizzled, all 512 threads) + inputs + ballot ----
  #pragma unroll
  for (int k = t; k < HH * 16 * CC; k += 512) {
    int c = k >> 8;
    int ji = k & 255;                        // j*16 + i
    int j = ji >> 4, i = ji & 15;
    int phys = (ji * CC + c) ^ ((ji >> 6) << 1);
    w_lds[phys] = ((const float4*)W1)[(size_t)(c * HH + j) * 32 + 16 + i];
  }
  if (t < CC * HH) w2_s[t] = W2[t];
  if (t < CC) b2_s[t] = b2[t];

  int r = -1, c0 = -1;
  if (tu < LL) {
    r = record_inputs[b * LL + tu];
    if (r >= 0) c0 = item_cat[r];
  }
  if (tu < DD) u_s[uu][tu] = user_emb[(size_t)user_inputs[b] * DD + tu];
  srow_sh[uu][tu] = 0;                       // pad slots -> row 0

  int myrank = 0;
  #pragma unroll
  for (int c = 0; c < CC; ++c) {
    unsigned long long m = __ballot(c0 == c);  // wave-wide; wave is user-pure
    if (lane == 0) wcnt[uu][wave][c] = __popcll(m);
    if (c0 == c) myrank = __popcll(m & ((1ULL << lane) - 1ULL));
  }
  __syncthreads();

  if (tu == 0) {                             // one thread per user
    int acc = 0;
    #pragma unroll
    for (int c = 0; c < CC; ++c) {
      cstart[uu][c] = acc;
      int cn = wcnt[uu][0][c] + wcnt[uu][1][c] + wcnt[uu][2][c] + wcnt[uu][3][c];
      ccnt[uu][c] = cn;
      acc = (acc + cn + 3) & ~3;             // 4-aligned groups
    }
    cstart[uu][CC] = acc;
  }
  if (tu < CC * HH) {                        // pre = b1 + W1u . u
    int c = tu / HH, j = tu % HH;
    const float* wp = &W1[(size_t)(c * HH + j) * (2 * DD)];
    float acc = b1[c * HH + j];
    #pragma unroll 8
    for (int d = 0; d < DD; ++d) acc += wp[d] * u_s[uu][d];
    pre_s[uu][c][j] = acc;
  }
  __syncthreads();

  if (c0 >= 0) {                             // stable scatter
    int off = cstart[uu][c0];
    for (int w = 0; w < wave; ++w) off += wcnt[uu][w][c0];
    srow_sh[uu][off + myrank] = r;
  }
  __syncthreads();

  // ---- Phase B: score; per-user thread = (grp, jq): 4 items x 4 hidden ----
  const int ntot = cstart[uu][CC];           // padded total (<= 228)
  {
    const int grp = tu >> 2, jq = tu & 3;
    const int q4 = grp * 4;
    if (q4 < ntot) {
      int c = 0;
      #pragma unroll
      for (int q = 0; q < CC - 1; ++q) c += (q4 >= cstart[uu][q + 1]) ? 1 : 0;

      const int r0 = srow_sh[uu][q4 + 0], r1 = srow_sh[uu][q4 + 1];
      const int r2 = srow_sh[uu][q4 + 2], r3 = srow_sh[uu][q4 + 3];
      const float4* e0 = (const float4*)&item_emb[(size_t)r0 * DD];
      const float4* e1 = (const float4*)&item_emb[(size_t)r1 * DD];
      const float4* e2 = (const float4*)&item_emb[(size_t)r2 * DD];
      const float4* e3 = (const float4*)&item_emb[(size_t)r3 * DD];

      float acc0[4], acc1[4], acc2[4], acc3[4];
      #pragma unroll
      for (int jj = 0; jj < 4; ++jj) {
        float pv = pre_s[uu][c][jq * 4 + jj];
        acc0[jj] = pv; acc1[jj] = pv; acc2[jj] = pv; acc3[jj] = pv;
      }

      #pragma unroll
      for (int i = 0; i < 16; ++i) {
        float4 a0 = e0[i], a1 = e1[i], a2 = e2[i], a3 = e3[i];
        #pragma unroll
        for (int jj = 0; jj < 4; ++jj) {
          int ji = (jq * 4 + jj) * 16 + i;
          float4 wv = w_lds[(ji * CC + c) ^ (jq << 1)];
          acc0[jj] += wv.x * a0.x + wv.y * a0.y + wv.z * a0.z + wv.w * a0.w;
          acc1[jj] += wv.x * a1.x + wv.y * a1.y + wv.z * a1.z + wv.w * a1.w;
          acc2[jj] += wv.x * a2.x + wv.y * a2.y + wv.z * a2.z + wv.w * a2.w;
          acc3[jj] += wv.x * a3.x + wv.y * a3.y + wv.z * a3.z + wv.w * a3.w;
        }
      }

      float s0 = 0.f, s1 = 0.f, s2 = 0.f, s3 = 0.f;
      #pragma unroll
      for (int jj = 0; jj < 4; ++jj) {
        float w2v = w2_s[c * HH + jq * 4 + jj];
        s0 += w2v * fmaxf(acc0[jj], 0.f);
        s1 += w2v * fmaxf(acc1[jj], 0.f);
        s2 += w2v * fmaxf(acc2[jj], 0.f);
        s3 += w2v * fmaxf(acc3[jj], 0.f);
      }
      s0 += __shfl_xor(s0, 1, 64); s0 += __shfl_xor(s0, 2, 64);
      s1 += __shfl_xor(s1, 1, 64); s1 += __shfl_xor(s1, 2, 64);
      s2 += __shfl_xor(s2, 1, 64); s2 += __shfl_xor(s2, 2, 64);
      s3 += __shfl_xor(s3, 1, 64); s3 += __shfl_xor(s3, 2, 64);

      if (jq == 0) {
        const float b2c = b2_s[c];
        *(float4*)&z_s[uu][q4] = make_float4(expf(s0 + b2c), expf(s1 + b2c),
                                             expf(s2 + b2c), expf(s3 + b2c));
      }
    }
  }
  __syncthreads();

  // ---- Phase C: gvec. per-user wave = category loop; lane (g,h) ----
  {
    const int g = (t >> 4) & 3, h = t & 15;  // within the 64-lane wave
    for (int c = wave; c < CC; c += NW) {
      const int i0 = cstart[uu][c], n = ccnt[uu][c];
      float4 acc = make_float4(0.f, 0.f, 0.f, 0.f);
      float  zs  = 0.f;
      const int kmax = (n + 3) >> 2;
      #pragma unroll 4
      for (int k = 0; k < kmax; ++k) {
        const int io = 4 * k + g;
        const int rr = srow_sh[uu][i0 + io];           // broadcast (4 addrs)
        const float zz = (io < n) ? z_s[uu][i0 + io] : 0.f;
        const float4 ev = *(const float4*)&item_emb[(size_t)rr * DD + 4 * h];
        acc.x += zz * ev.x; acc.y += zz * ev.y;
        acc.z += zz * ev.z; acc.w += zz * ev.w;
        zs += zz;                                      // uniform within h-group
      }
      acc.x += __shfl_xor(acc.x, 16, 64); acc.y += __shfl_xor(acc.y, 16, 64);
      acc.z += __shfl_xor(acc.z, 16, 64); acc.w += __shfl_xor(acc.w, 16, 64);
      acc.x += __shfl_xor(acc.x, 32, 64); acc.y += __shfl_xor(acc.y, 32, 64);
      acc.z += __shfl_xor(acc.z, 32, 64); acc.w += __shfl_xor(acc.w, 32, 64);
      zs += __shfl_xor(zs, 16, 64);
      zs += __shfl_xor(zs, 32, 64);

      if (g == 0) {
        const float inv = 1.f / fmaxf(zs, 1e-30f);
        gvec_s[uu][c][4 * h + 0] = acc.x * inv;
        gvec_s[uu][c][4 * h + 1] = acc.y * inv;
        gvec_s[uu][c][4 * h + 2] = acc.z * inv;
        gvec_s[uu][c][4 * h + 3] = acc.w * inv;        // empty cat -> 0
      }
    }
  }
  __syncthreads();

  // ---- Phase D: top-level attention + output ----
  if (tu < CC * HH) {
    int cc = tu / HH, j = tu % HH;
    const float* wp = &Wt1[(size_t)j * (2 * DD)];
    float a = bt1[j];
    #pragma unroll 8
    for (int d = 0; d < DD; ++d) a += wp[d] * u_s[uu][d];
    #pragma unroll 8
    for (int d = 0; d < DD; ++d) a += wp[DD + d] * gvec_s[uu][cc][d];
    h2_s[uu][cc][j] = fmaxf(a, 0.f);
  }
  __syncthreads();

  if (tu == 0) {
    float s2[CC];
    float m = -INFINITY;
    #pragma unroll
    for (int cc = 0; cc < CC; ++cc) {
      float a = bt2[0];
      #pragma unroll
      for (int j = 0; j < HH; ++j) a += Wt2[j] * h2_s[uu][cc][j];
      s2[cc] = a;
      if (ccnt[uu][cc] > 0) m = fmaxf(m, a);
    }
    if (m == -INFINITY) m = 0.f;
    float sum = 0.f;
    float z2[CC];
    #pragma unroll
    for (int cc = 0; cc < CC; ++cc) {
      z2[cc] = (ccnt[uu][cc] > 0) ? expf(s2[cc] - m) : 0.f;
      sum += z2[cc];
    }
    float inv = 1.f / fmaxf(sum, 1e-30f);
    #pragma unroll
    for (int cc = 0; cc < CC; ++cc) w2t_s[uu][cc] = z2[cc] * inv;
  }
  __syncthreads();

  if (tu < DD) {                              // one full wave per user
    float hy = 0.f;
    #pragma unroll
    for (int cc = 0; cc < CC; ++cc) hy += w2t_s[uu][cc] * gvec_s[uu][cc][tu];
    float ti = item_emb[(size_t)item_inputs[b] * DD + tu];
    float prod = hy * ti;
    #pragma unroll
    for (int off = 32; off > 0; off >>= 1)
      prod += __shfl_down(prod, off, 64);
    if (tu == 0) out[b] = prod;
  }
}

extern "C" void kernel_launch(void* const* d_in, const int* in_sizes, int n_in,
                              void* d_out, int out_size, void* d_ws, size_t ws_size,
                              hipStream_t stream) {
  const int*   user_inputs   = (const int*)d_in[0];
  const int*   record_inputs = (const int*)d_in[1];
  const int*   item_inputs   = (const int*)d_in[2];
  const int*   item_cat      = (const int*)d_in[3];
  const float* user_emb      = (const float*)d_in[4];
  const float* item_emb      = (const float*)d_in[5];
  const float* W1            = (const float*)d_in[6];
  const float* b1            = (const float*)d_in[7];
  const float* W2            = (const float*)d_in[8];
  const float* b2            = (const float*)d_in[9];
  const float* Wt1           = (const float*)d_in[10];
  const float* bt1           = (const float*)d_in[11];
  const float* Wt2           = (const float*)d_in[12];
  const float* bt2           = (const float*)d_in[13];
  float* out = (float*)d_out;

  din_fused<<<NB / UPB, 512, 0, stream>>>(user_inputs, record_inputs, item_inputs,
                                          item_cat, user_emb, item_emb,
                                          W1, b1, W2, b2, Wt1, bt1, Wt2, bt2, out);
}